// Round 1
// baseline (1554.590 us; speedup 1.0000x reference)
//
#include <hip/hip_runtime.h>
#include <hip/hip_bf16.h>
#include <cstdint>
#include <cstddef>

// Problem constants
// B=2048, D=256, H=256, N=64, F=513, 4H=1024

typedef short s16x8 __attribute__((ext_vector_type(8)));
typedef float f32x4 __attribute__((ext_vector_type(4)));

static __device__ __forceinline__ unsigned short f2b(float f){
  union{float f; unsigned int u;} v; v.f = f;
  unsigned int r = v.u + 0x7fffu + ((v.u >> 16) & 1u);   // RNE
  return (unsigned short)(r >> 16);
}
static __device__ __forceinline__ float b2f(unsigned short h){
  union{unsigned int u; float f;} v; v.u = ((unsigned int)h) << 16; return v.f;
}
static __device__ __forceinline__ unsigned int pack2(float a, float b){
  return (unsigned int)f2b(a) | ((unsigned int)f2b(b) << 16);
}
static __device__ __forceinline__ float fsig(float x){ return 1.0f / (1.0f + __expf(-x)); }
static __device__ __forceinline__ float ftanh(float x){ return 2.0f / (1.0f + __expf(-2.0f * x)) - 1.0f; }
static __device__ __forceinline__ float wred(float p){
  p += __shfl_down(p, 32); p += __shfl_down(p, 16); p += __shfl_down(p, 8);
  p += __shfl_down(p, 4);  p += __shfl_down(p, 2);  p += __shfl_down(p, 1);
  return p;
}

// ---------------------------------------------------------------------------
// K0: weight prep. WihBf: bf16 (1024 x 512, K-major). wlast = W_ih[:,512].
// bias = b_ih + b_hh. wfrag: W_hh pre-swizzled into MFMA B-fragment order:
// frag = (w*8+nt)*8+kt owns cols w*128+nt*16+(lane&15), k = kt*32+(lane>>4)*8+j.
// ---------------------------------------------------------------------------
__global__ __launch_bounds__(256) void k_prep(
    const float* __restrict__ wih, const float* __restrict__ whh,
    const float* __restrict__ bih, const float* __restrict__ bhh,
    unsigned short* __restrict__ wihbf, unsigned short* __restrict__ wfrag,
    float* __restrict__ bias, float* __restrict__ wlast){
  int id = blockIdx.x * 256 + threadIdx.x;          // grid = 2048*256 = 524288
  { // WihBf: 1024*512 elements, id covers exactly
    int j = id >> 9, k = id & 511;
    wihbf[id] = f2b(wih[j * 513 + k]);
  }
  if (id < 262144){ // wfrag: 512 frags * 64 lanes * 8 elems
    int frag = id >> 9;
    int lane = (id >> 3) & 63;
    int j    = id & 7;
    int w  = frag >> 6;
    int nt = (frag >> 3) & 7;
    int kt = frag & 7;
    int colg = w * 128 + nt * 16 + (lane & 15);
    int k    = kt * 32 + (lane >> 4) * 8 + j;
    wfrag[frag * 512 + lane * 8 + j] = f2b(whh[colg * 256 + k]);
  }
  if (id < 1024){
    bias[id]  = bih[id] + bhh[id];
    wlast[id] = wih[id * 513 + 512];
  }
}

// ---------------------------------------------------------------------------
// K1: routing. One block per batch row.
// q = Wq x ; qk = Wk^T q ; sims[n] = slots[n]·qk ; v = Wv x + bv
// idx = first empty slot if any (prob ~1), else argmax(sims) (first max).
// Also writes delta_out and filled_out.
// ---------------------------------------------------------------------------
__global__ __launch_bounds__(256) void k_route(
    const float* __restrict__ x, const float* __restrict__ slots,
    const float* __restrict__ delta, const int* __restrict__ filled,
    const float* __restrict__ Wq, const float* __restrict__ Wk,
    const float* __restrict__ Wv, const float* __restrict__ bv,
    int* __restrict__ idx_ws, float* __restrict__ v_ws,
    float* __restrict__ delta_out, float* __restrict__ filled_out){
  int b = blockIdx.x, tid = threadIdx.x, l = tid & 63, w = tid >> 6;
  __shared__ float xs[256], qs[256], qks[256], sims[64];
  __shared__ int sidx;
  xs[tid] = x[b * 256 + tid];
  __syncthreads();
  // q and v: wave w handles outputs [w*64, w*64+64); coalesced weight reads
  for (int t = 0; t < 64; ++t){
    int h = w * 64 + t;
    float p = 0.f, pv = 0.f;
    #pragma unroll
    for (int j2 = 0; j2 < 4; ++j2){
      float xv = xs[l + 64 * j2];
      p  += Wq[h * 256 + l + 64 * j2] * xv;
      pv += Wv[h * 256 + l + 64 * j2] * xv;
    }
    p = wred(p); pv = wred(pv);
    if (l == 0){ qs[h] = p; v_ws[b * 256 + h] = pv + bv[h]; }
  }
  __syncthreads();
  { // qk[d] = sum_h q[h] * Wk[h][d]  (coalesced across d)
    int d = tid; float p = 0.f;
    for (int h = 0; h < 256; ++h) p += qs[h] * Wk[h * 256 + d];
    qks[d] = p;
  }
  __syncthreads();
  for (int t = 0; t < 16; ++t){
    int n = w * 16 + t;
    float p = 0.f;
    #pragma unroll
    for (int j2 = 0; j2 < 4; ++j2)
      p += slots[(size_t)(b * 64 + n) * 256 + l + 64 * j2] * qks[l + 64 * j2];
    p = wred(p);
    if (l == 0) sims[n] = p;
  }
  __syncthreads();
  if (tid == 0){
    int ie = -1;
    for (int n = 0; n < 64; ++n) if (!filled[b * 64 + n]){ ie = n; break; }
    int ic = 0; float best = sims[0];
    for (int n = 1; n < 64; ++n) if (sims[n] > best){ best = sims[n]; ic = n; }
    int id = (ie >= 0) ? ie : ic;
    sidx = id; idx_ws[b] = id;
  }
  __syncthreads();
  if (tid < 64){
    int n = tid; bool sel = (n == sidx);
    delta_out[b * 64 + n]  = sel ? 0.0f : (delta[b * 64 + n] + 1.0f);
    filled_out[b * 64 + n] = (sel || filled[b * 64 + n] != 0) ? 1.0f : 0.0f;
  }
}

// ---------------------------------------------------------------------------
// K2: scatter/copy. slots_out / cum_out with the selected row replaced.
// ---------------------------------------------------------------------------
__global__ __launch_bounds__(256) void k_scatter(
    const float* __restrict__ x, const float* __restrict__ slots,
    const float* __restrict__ cum, const int* __restrict__ idx_ws,
    const float* __restrict__ v_ws,
    float* __restrict__ slots_out, float* __restrict__ cum_out){
  int row = blockIdx.x * 4 + (threadIdx.x >> 6);   // global (b,n) row
  int l = threadIdx.x & 63;
  int b = row >> 6, n = row & 63;
  size_t e = (size_t)row * 256 + l * 4;
  float4 s  = *(const float4*)(slots + e);
  float4 cf = *(const float4*)(cum + e);
  float4 xv = *(const float4*)(x + b * 256 + l * 4);
  if (n == idx_ws[b]){
    s  = *(const float4*)(v_ws + b * 256 + l * 4);
    cf = xv;
  } else {
    cf.x += xv.x; cf.y += xv.y; cf.z += xv.z; cf.w += xv.w;
  }
  *(float4*)(slots_out + e) = s;
  *(float4*)(cum_out + e)   = cf;
}

// ---------------------------------------------------------------------------
// K3: Z0 = mem_seq @ W_ih^T + delta⊗wlast + bias  -> bf16 (131072 x 1024)
// 128x128 tile, BK=32, 4 waves, mfma_f32_16x16x32_bf16, single-buffered LDS.
// A rows: k<256 from slots_out, k>=256 from cum_out (fp32 -> bf16 on stage).
// ---------------------------------------------------------------------------
__global__ __launch_bounds__(256) void k_gemm(
    const float* __restrict__ Asl, const float* __restrict__ Acu,
    const float* __restrict__ dlt,
    const unsigned short* __restrict__ wihbf,
    const float* __restrict__ wlast, const float* __restrict__ bias,
    unsigned short* __restrict__ z0){
  __shared__ unsigned short As[128 * 32];
  __shared__ unsigned short Bs[128 * 32];
  int tid = threadIdx.x;
  int n0 = blockIdx.x * 128, m0 = blockIdx.y * 128;
  int l = tid & 63, wid = tid >> 6, wm = wid & 1, wn = wid >> 1;
  f32x4 acc[4][4];
  #pragma unroll
  for (int mi = 0; mi < 4; ++mi)
    #pragma unroll
    for (int ni = 0; ni < 4; ++ni){ f32x4 zr = {0.f,0.f,0.f,0.f}; acc[mi][ni] = zr; }

  int r = tid >> 1, half = tid & 1;
  for (int k0 = 0; k0 < 512; k0 += 32){
    // stage A (fp32 -> bf16)
    {
      int ks = k0 + half * 16;
      const float* src = (ks < 256) ? (Asl + (size_t)(m0 + r) * 256 + ks)
                                    : (Acu + (size_t)(m0 + r) * 256 + (ks - 256));
      float4 f0 = ((const float4*)src)[0];
      float4 f1 = ((const float4*)src)[1];
      float4 f2 = ((const float4*)src)[2];
      float4 f3 = ((const float4*)src)[3];
      uint4 w0, w1;
      w0.x = pack2(f0.x, f0.y); w0.y = pack2(f0.z, f0.w);
      w0.z = pack2(f1.x, f1.y); w0.w = pack2(f1.z, f1.w);
      w1.x = pack2(f2.x, f2.y); w1.y = pack2(f2.z, f2.w);
      w1.z = pack2(f3.x, f3.y); w1.w = pack2(f3.z, f3.w);
      uint4* dstA = (uint4*)&As[r * 32 + half * 16];
      dstA[0] = w0; dstA[1] = w1;
    }
    // stage B (already bf16)
    {
      const uint4* bsrc = (const uint4*)(wihbf + (size_t)(n0 + r) * 512 + k0 + half * 16);
      uint4* dstB = (uint4*)&Bs[r * 32 + half * 16];
      dstB[0] = bsrc[0]; dstB[1] = bsrc[1];
    }
    __syncthreads();
    s16x8 a[4], bb[4];
    #pragma unroll
    for (int mi = 0; mi < 4; ++mi)
      a[mi] = *(const s16x8*)&As[(wm * 64 + mi * 16 + (l & 15)) * 32 + (l >> 4) * 8];
    #pragma unroll
    for (int ni = 0; ni < 4; ++ni)
      bb[ni] = *(const s16x8*)&Bs[(wn * 64 + ni * 16 + (l & 15)) * 32 + (l >> 4) * 8];
    #pragma unroll
    for (int mi = 0; mi < 4; ++mi)
      #pragma unroll
      for (int ni = 0; ni < 4; ++ni)
        acc[mi][ni] = __builtin_amdgcn_mfma_f32_16x16x32_bf16(a[mi], bb[ni], acc[mi][ni], 0, 0, 0);
    __syncthreads();
  }
  // epilogue: + delta*wlast + bias, store bf16
  #pragma unroll
  for (int mi = 0; mi < 4; ++mi){
    int rbase = m0 + wm * 64 + mi * 16 + (l >> 4) * 4;
    #pragma unroll
    for (int reg = 0; reg < 4; ++reg){
      float dv = dlt[rbase + reg];
      #pragma unroll
      for (int ni = 0; ni < 4; ++ni){
        int gc = n0 + wn * 64 + ni * 16 + (l & 15);
        float val = acc[mi][ni][reg] + dv * wlast[gc] + bias[gc];
        z0[(size_t)(rbase + reg) * 1024 + gc] = f2b(val);
      }
    }
  }
}

// ---------------------------------------------------------------------------
// K4: recurrent LSTM. 128 blocks x 512 threads (8 waves), 16 batch rows/block.
// W_hh streamed from pre-swizzled fragment buffer (L2-resident).
// h kept as XOR-swizzled bf16 in LDS; z tile (16x1024 f32) in LDS; c in regs.
// ---------------------------------------------------------------------------
__global__ __launch_bounds__(512) void k_lstm(
    const unsigned short* __restrict__ z0,
    const unsigned short* __restrict__ wfrag,
    float* __restrict__ hm){
  extern __shared__ unsigned char smem[];
  float* zl = (float*)smem;                       // 16*1024 f32 = 64KB
  unsigned char* hbf = smem + 65536;              // 16*256 bf16 = 8KB, swizzled
  int tid = threadIdx.x, l = tid & 63, wid = tid >> 6;
  int b0 = blockIdx.x * 16;
  for (int i = tid; i < 2048; i += 512) ((unsigned int*)hbf)[i] = 0u;
  float cst[8];
  #pragma unroll
  for (int i = 0; i < 8; ++i) cst[i] = 0.f;
  int gc_c = tid & 255;     // gate column
  int rgrp = tid >> 8;      // 0/1 -> rows rgrp*8 .. +7
  int arow = l & 15;
  __syncthreads();

  for (int n = 0; n < 64; ++n){
    // ---- MFMA phase: z = h_{n-1} @ W_hh^T for this block's 16 rows ----
    s16x8 a[8];
    #pragma unroll
    for (int kt = 0; kt < 8; ++kt){
      int byteo = ((arow * 512) + kt * 64 + ((l >> 4) * 16)) ^ ((arow & 7) << 4);
      a[kt] = *(const s16x8*)(hbf + byteo);
    }
    #pragma unroll
    for (int nt = 0; nt < 8; ++nt){
      f32x4 acc = {0.f, 0.f, 0.f, 0.f};
      #pragma unroll
      for (int kt = 0; kt < 8; ++kt){
        const s16x8* bf = (const s16x8*)(wfrag + (size_t)((wid * 8 + nt) * 8 + kt) * 512 + l * 8);
        acc = __builtin_amdgcn_mfma_f32_16x16x32_bf16(a[kt], *bf, acc, 0, 0, 0);
      }
      int colg = wid * 128 + nt * 16 + (l & 15);
      int rw = (l >> 4) * 4;
      #pragma unroll
      for (int reg = 0; reg < 4; ++reg)
        zl[(rw + reg) * 1024 + colg] = acc[reg];
    }
    __syncthreads();
    // ---- gate phase ----
    #pragma unroll
    for (int rr8 = 0; rr8 < 8; ++rr8){
      int rr = rgrp * 8 + rr8;
      size_t zrow = ((size_t)(b0 + rr) * 64 + n) * 1024;
      float zi = zl[rr * 1024 + gc_c]       + b2f(z0[zrow + gc_c]);
      float zf = zl[rr * 1024 + 256 + gc_c] + b2f(z0[zrow + 256 + gc_c]);
      float zg = zl[rr * 1024 + 512 + gc_c] + b2f(z0[zrow + 512 + gc_c]);
      float zo = zl[rr * 1024 + 768 + gc_c] + b2f(z0[zrow + 768 + gc_c]);
      float cv = fsig(zf) * cst[rr8] + fsig(zi) * ftanh(zg);
      cst[rr8] = cv;
      float hv = fsig(zo) * ftanh(cv);
      int hb = ((rr * 512 + gc_c * 2) ^ ((rr & 7) << 4));
      *(unsigned short*)(hbf + hb) = f2b(hv);
      if (n == 63) hm[(size_t)(b0 + rr) * 256 + gc_c] = hv;
    }
    __syncthreads();
  }
}

// ---------------------------------------------------------------------------
extern "C" void kernel_launch(void* const* d_in, const int* in_sizes, int n_in,
                              void* d_out, int out_size, void* d_ws, size_t ws_size,
                              hipStream_t stream){
  const float* x      = (const float*)d_in[0];
  // d_in[1] = h_mem_prev (unused by reference)
  const float* slots  = (const float*)d_in[2];
  const float* cum    = (const float*)d_in[3];
  const float* delta  = (const float*)d_in[4];
  const int*   filled = (const int*)d_in[5];
  const float* Wq  = (const float*)d_in[6];
  const float* Wk  = (const float*)d_in[7];
  const float* Wv  = (const float*)d_in[8];
  const float* bv  = (const float*)d_in[9];
  const float* wih = (const float*)d_in[10];
  const float* whh = (const float*)d_in[11];
  const float* bih = (const float*)d_in[12];
  const float* bhh = (const float*)d_in[13];

  float* out        = (float*)d_out;
  float* hm         = out;                 // (B,H)    524288
  float* slots_out  = out + 524288;        // (B,N,D)  33554432
  float* cum_out    = out + 34078720;      // (B,N,D)  33554432
  float* delta_out  = out + 67633152;      // (B,N)    131072
  float* filled_out = out + 67764224;      // (B,N)    131072

  char* ws = (char*)d_ws;
  int*            idx_ws = (int*)ws;                                   // 8KB
  float*          v_ws   = (float*)(ws + 8192);                        // 2MB
  float*          bias   = (float*)(ws + 2105344);                     // 4KB
  float*          wlast  = (float*)(ws + 2109440);                     // 4KB
  unsigned short* wihbf  = (unsigned short*)(ws + 2113536);            // 1MB
  unsigned short* wfrag  = (unsigned short*)(ws + 3162112);            // 512KB
  unsigned short* z0     = (unsigned short*)(ws + 3686400);            // 256MB

  k_prep<<<dim3(2048), dim3(256), 0, stream>>>(wih, whh, bih, bhh, wihbf, wfrag, bias, wlast);
  k_route<<<dim3(2048), dim3(256), 0, stream>>>(x, slots, delta, filled, Wq, Wk, Wv, bv,
                                                idx_ws, v_ws, delta_out, filled_out);
  k_scatter<<<dim3(32768), dim3(256), 0, stream>>>(x, slots, cum, idx_ws, v_ws,
                                                   slots_out, cum_out);
  k_gemm<<<dim3(8, 1024), dim3(256), 0, stream>>>(slots_out, cum_out, delta_out,
                                                  wihbf, wlast, bias, z0);
  k_lstm<<<dim3(128), dim3(512), 73728, stream>>>(z0, wfrag, hm);
}